// Round 10
// baseline (49.572 us; speedup 1.0000x reference)
//
#include <hip/hip_runtime.h>

// Conv4d via implicit GEMM on MFMA (bf16 in, fp32 accum), FULLY FUSED.
// x (2,16,20^4) f32, w (16,32,3^4) f32 -> out (2,32,18^4) f32
//
// R10 vs R9: occupancy fix. R9 used 124 VGPR + 144 acc AGPR = 268 unified
// regs -> 1 wave/SIMD (Occupancy 13.8%), MfmaUtil 16%, pure latency-bound.
// Changes:
//  (1) af[9] (36 VGPR) -> LDS: per-ab 9.2KB wt tap-block staged via
//      global_load_lds (double-buffered, prefetched one ab ahead); A-frags
//      are contiguous-1KB ds_read_b128 spans (conflict-free).
//  (2) val[16] (32 VGPR) -> 2 batches of 8 ic (16 VGPR peak), interleaved
//      with the 3 c-phases of MFMA (write-to-inactive-buffer is safe any
//      time after the step's start barrier).
// Target ~230 regs/wave -> 2 waves/SIMD -> 2 blocks/CU latency hiding.
// Keeps: d-shift (9 B-reads -> 27 MFMA per ab), XCD swizzle, swizzled LDS
// writes (R9 bijection), shfl+edgebuf epilogue, launch_bounds(256,2).

typedef unsigned short ushort_t;
typedef __attribute__((ext_vector_type(8)))  __bf16 bf16x8;
typedef __attribute__((ext_vector_type(16))) float  f32x16;
typedef __attribute__((ext_vector_type(4)))  unsigned int uint4v;

__device__ __forceinline__ ushort_t f2bf(float f) {
    union { float f; unsigned int u; } v; v.f = f;
    unsigned int r = v.u + 0x7FFFu + ((v.u >> 16) & 1u);   // RNE
    return (ushort_t)(r >> 16);
}

__device__ __forceinline__ void gload16(const ushort_t* g, ushort_t* l) {
    __builtin_amdgcn_global_load_lds(
        (const __attribute__((address_space(1))) unsigned int*)g,
        (__attribute__((address_space(3))) unsigned int*)l, 16, 0, 0);
}

// ---------- mini-prepass: w (ic,oc,tap f32) -> wt (tap,oc,ic bf16) ----------
__global__ __launch_bounds__(256) void prep_w(const float* __restrict__ w,
                                              ushort_t* __restrict__ wt) {
    int s = blockIdx.x * 256 + threadIdx.x;
    if (s < 41472) {
        int ic = s / 2592, rem = s % 2592;
        int oc = rem / 81, tap = rem % 81;
        wt[tap * 512 + oc * 16 + ic] = f2bf(w[s]);
    }
}

// ---------- fused conv ----------
__global__ __launch_bounds__(256, 2) void conv4d_fused(
    const float* __restrict__ x, const ushort_t* __restrict__ wt,
    float* __restrict__ out)
{
    __shared__ ushort_t lx[2][6400];        // double-buffered x slab, 12.8KB each
    __shared__ ushort_t lwt[2][4608];       // double-buffered wt tap-block, 9.2KB each
    __shared__ float edgebuf[4][3][2][16];  // [wv][e1|e2a|e2b][ic8][r]

    // bijective XCD swizzle: 648 blocks = 8 XCDs x 81 contiguous tiles
    const int wgid = blockIdx.x;
    const int tile_ = (wgid & 7) * 81 + (wgid >> 3);
    const int n = tile_ / 324;
    const int rem_ = tile_ - n * 324;
    const int j = rem_ / 18, i = rem_ % 18;

    const int t = threadIdx.x;
    const int lane = t & 63, wv = t >> 6;
    const int col = lane & 31, ic8 = lane >> 5;

    // slab-pos per tile m; reads at spc + c*20 (<= +40); clamp base to 359
    int sp[3]; int cb[3];
    #pragma unroll
    for (int m = 0; m < 3; ++m) {
        sp[m] = (3 * wv + m) * 32 + col;
        const int spc = sp[m] > 359 ? 359 : sp[m];
        cb[m] = spc * 32 + ic8 * 16;       // logical BYTES into slab
    }

    f32x16 acc[3][3];   // [d][m]
    #pragma unroll
    for (int d = 0; d < 3; ++d)
        #pragma unroll
        for (int m = 0; m < 3; ++m)
            #pragma unroll
            for (int r = 0; r < 16; ++r) acc[d][m][r] = 0.0f;

    const float* xn = x + (size_t)n * 2560000;
    const bool stg = (t < 200);
    const int p0 = 2 * t;
    // per-thread swizzled LDS write base; chunks go at wphys ^ (c*16)
    const int wlog = 64 * t;
    const int wphys = wlog ^ (((wlog >> 7) & 7) << 4);

    // A-frag byte offset within a tap block (ds_read; any per-lane addr ok)
    const int aoff = col * 32 + ic8 * 16;

    // prologue: stage wt block 0 + x slab (a=0,b=0)
    {
        const ushort_t* g = wt;                   // taps 0..8
        gload16(g + t * 8,        lwt[0] + (wv << 9));
        gload16(g + 2048 + t * 8, lwt[0] + 2048 + (wv << 9));
        if (t < 64) gload16(g + 4096 + t * 8, lwt[0] + 4096);
    }
    if (stg) {
        const float* xr = xn + (size_t)i * 8000 + (size_t)j * 400 + p0;
        float2 v[16];
        #pragma unroll
        for (int ic = 0; ic < 16; ++ic)
            v[ic] = *(const float2*)(xr + (size_t)ic * 160000);
        char* base = (char*)lx[0];
        uint4v c0, c1, c2, c3;
        #pragma unroll
        for (int m = 0; m < 4; ++m) {
            c0[m] = (unsigned)f2bf(v[2*m].x)   | ((unsigned)f2bf(v[2*m+1].x) << 16);
            c1[m] = (unsigned)f2bf(v[2*m+8].x) | ((unsigned)f2bf(v[2*m+9].x) << 16);
            c2[m] = (unsigned)f2bf(v[2*m].y)   | ((unsigned)f2bf(v[2*m+1].y) << 16);
            c3[m] = (unsigned)f2bf(v[2*m+8].y) | ((unsigned)f2bf(v[2*m+9].y) << 16);
        }
        *(uint4v*)(base + (wphys ^ 0))  = c0;
        *(uint4v*)(base + (wphys ^ 16)) = c1;
        *(uint4v*)(base + (wphys ^ 32)) = c2;
        *(uint4v*)(base + (wphys ^ 48)) = c3;
    }

    int cur = 0;
    for (int ab = 0; ab < 9; ++ab) {
        __syncthreads();   // drains vmcnt: slab[cur] & lwt[cur&1... prefetch] ready

        const int nxt = ab + 1;
        // prefetch next wt tap-block into lwt[nxt&1]
        if (ab < 8) {
            const ushort_t* g = wt + (size_t)nxt * 4608;
            ushort_t* l = lwt[nxt & 1];
            gload16(g + t * 8,        l + (wv << 9));
            gload16(g + 2048 + t * 8, l + 2048 + (wv << 9));
            if (t < 64) gload16(g + 4096 + t * 8, l + 4096);
        }

        const float* xr = (ab < 8)
            ? xn + (size_t)(i + nxt / 3) * 8000 + (size_t)(j + nxt % 3) * 400 + p0
            : nullptr;

        // issue val batch 1 (ic 0..7)
        float2 v1[8];
        if (ab < 8 && stg) {
            #pragma unroll
            for (int ic = 0; ic < 8; ++ic)
                v1[ic] = *(const float2*)(xr + (size_t)ic * 160000);
        }

        const char* lbase = (const char*)lx[cur];
        const char* wbase = (const char*)lwt[ab & 1];

        // ---- c = 0 ----
        {
            bf16x8 af0 = *(const bf16x8*)(wbase + 0 * 1024 + aoff);
            bf16x8 af1 = *(const bf16x8*)(wbase + 1 * 1024 + aoff);
            bf16x8 af2 = *(const bf16x8*)(wbase + 2 * 1024 + aoff);
            #pragma unroll
            for (int m = 0; m < 3; ++m) {
                const int lg = cb[m];
                const int ph = lg ^ (((lg >> 7) & 7) << 4);
                bf16x8 bv = *(const bf16x8*)(lbase + ph);
                acc[0][m] = __builtin_amdgcn_mfma_f32_32x32x16_bf16(af0, bv, acc[0][m], 0, 0, 0);
                acc[1][m] = __builtin_amdgcn_mfma_f32_32x32x16_bf16(af1, bv, acc[1][m], 0, 0, 0);
                acc[2][m] = __builtin_amdgcn_mfma_f32_32x32x16_bf16(af2, bv, acc[2][m], 0, 0, 0);
            }
        }

        // write chunks 0,2 (pos p0 / p0+1, ic 0-7); issue batch 2
        float2 v2[8];
        if (ab < 8 && stg) {
            char* base = (char*)lx[cur ^ 1];
            uint4v c0, c2;
            #pragma unroll
            for (int m = 0; m < 4; ++m) {
                c0[m] = (unsigned)f2bf(v1[2*m].x) | ((unsigned)f2bf(v1[2*m+1].x) << 16);
                c2[m] = (unsigned)f2bf(v1[2*m].y) | ((unsigned)f2bf(v1[2*m+1].y) << 16);
            }
            *(uint4v*)(base + (wphys ^ 0))  = c0;
            *(uint4v*)(base + (wphys ^ 32)) = c2;
            #pragma unroll
            for (int ic = 0; ic < 8; ++ic)
                v2[ic] = *(const float2*)(xr + (size_t)(ic + 8) * 160000);
        }

        // ---- c = 1, 2 ----
        #pragma unroll
        for (int c = 1; c < 3; ++c) {
            bf16x8 af0 = *(const bf16x8*)(wbase + (c * 3 + 0) * 1024 + aoff);
            bf16x8 af1 = *(const bf16x8*)(wbase + (c * 3 + 1) * 1024 + aoff);
            bf16x8 af2 = *(const bf16x8*)(wbase + (c * 3 + 2) * 1024 + aoff);
            #pragma unroll
            for (int m = 0; m < 3; ++m) {
                const int lg = cb[m] + c * 640;
                const int ph = lg ^ (((lg >> 7) & 7) << 4);
                bf16x8 bv = *(const bf16x8*)(lbase + ph);
                acc[0][m] = __builtin_amdgcn_mfma_f32_32x32x16_bf16(af0, bv, acc[0][m], 0, 0, 0);
                acc[1][m] = __builtin_amdgcn_mfma_f32_32x32x16_bf16(af1, bv, acc[1][m], 0, 0, 0);
                acc[2][m] = __builtin_amdgcn_mfma_f32_32x32x16_bf16(af2, bv, acc[2][m], 0, 0, 0);
            }
        }

        // write chunks 1,3 (ic 8-15)
        if (ab < 8) {
            if (stg) {
                char* base = (char*)lx[cur ^ 1];
                uint4v c1, c3;
                #pragma unroll
                for (int m = 0; m < 4; ++m) {
                    c1[m] = (unsigned)f2bf(v2[2*m].x) | ((unsigned)f2bf(v2[2*m+1].x) << 16);
                    c3[m] = (unsigned)f2bf(v2[2*m].y) | ((unsigned)f2bf(v2[2*m+1].y) << 16);
                }
                *(uint4v*)(base + (wphys ^ 16)) = c1;
                *(uint4v*)(base + (wphys ^ 48)) = c3;
            }
            cur ^= 1;
        }
    }

    // ---- epilogue: out(k,l) = acc0[s] + acc1[s+1] + acc2[s+2], s=k*20+l ----
    if (col == 0) {
        #pragma unroll
        for (int r = 0; r < 16; ++r) {
            edgebuf[wv][0][ic8][r] = acc[1][0][r];
            edgebuf[wv][1][ic8][r] = acc[2][0][r];
        }
    } else if (col == 1) {
        #pragma unroll
        for (int r = 0; r < 16; ++r)
            edgebuf[wv][2][ic8][r] = acc[2][0][r];
    }
    __syncthreads();
    const int nw = wv < 3 ? wv + 1 : 3;   // wave3's import is never consumed

    bool valm[3]; float* po[3];
    float* outn = out + (size_t)n * 3359232 + (size_t)i * 5832 + (size_t)j * 324
                      + (size_t)ic8 * 419904;
    #pragma unroll
    for (int m = 0; m < 3; ++m) {
        const int s = sp[m];
        const int k = s / 20, ls = s % 20;
        valm[m] = (ls <= 17) && (s <= 357);
        po[m] = outn + k * 18 + ls;
    }
    const int src1 = (lane & 32) | ((col + 1) & 31);
    const int src2 = (lane & 32) | ((col + 2) & 31);

    #pragma unroll
    for (int r = 0; r < 16; ++r) {
        const float e1  = edgebuf[nw][0][ic8][r];
        const float e2a = edgebuf[nw][1][ic8][r];
        const float e2b = edgebuf[nw][2][ic8][r];
        float t1[4], t2[4];
        #pragma unroll
        for (int m = 0; m < 3; ++m) {
            t1[m] = __shfl(acc[1][m][r], src1, 64);
            t2[m] = __shfl(acc[2][m][r], src2, 64);
        }
        t1[3] = e1;
        t2[3] = (col == 30) ? e2a : e2b;
        const int offr = ((r & 3) + 8 * (r >> 2)) * 104976;
        #pragma unroll
        for (int m = 0; m < 3; ++m) {
            const float v1m = (col == 31) ? t1[m + 1] : t1[m];
            const float v2m = (col >= 30) ? t2[m + 1] : t2[m];
            const float res = acc[0][m][r] + v1m + v2m;
            if (valm[m]) po[m][offr] = res;
        }
    }
}

extern "C" void kernel_launch(void* const* d_in, const int* in_sizes, int n_in,
                              void* d_out, int out_size, void* d_ws, size_t ws_size,
                              hipStream_t stream) {
    const float* x = (const float*)d_in[0];
    const float* w = (const float*)d_in[1];
    float* out = (float*)d_out;

    ushort_t* wt = (ushort_t*)d_ws;   // 83 KB

    prep_w<<<dim3(162), 256, 0, stream>>>(w, wt);
    conv4d_fused<<<dim3(648), 256, 0, stream>>>(x, wt, out);
}

// Round 11
// 44.602 us; speedup vs baseline: 1.1114x; 1.1114x over previous
//
#include <hip/hip_runtime.h>

// Conv4d via implicit GEMM on MFMA (bf16 in, fp32 accum).
// x (2,16,20^4) f32, w (16,32,3^4) f32 -> out (2,32,18^4) f32
//
// R11 vs R10: cross the 256-unified-reg occupancy cliff for real.
// R9: 124 VGPR + 144 AGPR = 268 -> 1 wave/SIMD. R10: 116 + 144 = 260 ->
// STILL 1 wave/SIMD (needed VGPR <= 112). Fix: remove ALL register staging
// from the conv. xt (NHWC bf16) intermediate reinstated (R5/R7-verified
// prepass) so the slab stages via global_load_lds (0 VGPR, linear LDS,
// contiguous-1KB B-reads, no swizzle needed); lwt also via global_load_lds.
// Live VGPR ~70-90 + 144 AGPR ~= 214 <= 256 -> 2 waves/SIMD, 2 blocks/CU.
// Also: wt re-laid as [tap][ic8][oc][ic_lo] so A-frag ds_reads sweep one
// contiguous 1024B span/wave (R10's col*32 stride was ~8-way conflicted,
// SQ_LDS_BANK_CONFLICT 1.6M).
// Keeps: d-shift (9 B-reads + 9 A-reads -> 27 MFMA per ab), XCD swizzle,
// shfl+edgebuf epilogue (verified R4/R6/R7/R9/R10), acc[3][3] static unroll.

typedef unsigned short ushort_t;
typedef __attribute__((ext_vector_type(8)))  __bf16 bf16x8;
typedef __attribute__((ext_vector_type(16))) float  f32x16;
typedef __attribute__((ext_vector_type(4)))  unsigned int uint4v;

__device__ __forceinline__ ushort_t f2bf(float f) {
    union { float f; unsigned int u; } v; v.f = f;
    unsigned int r = v.u + 0x7FFFu + ((v.u >> 16) & 1u);   // RNE
    return (ushort_t)(r >> 16);
}

__device__ __forceinline__ void gload16(const ushort_t* g, ushort_t* l) {
    __builtin_amdgcn_global_load_lds(
        (const __attribute__((address_space(1))) unsigned int*)g,
        (__attribute__((address_space(3))) unsigned int*)l, 16, 0, 0);
}

// ---------- fused prepass ----------
// blocks 0..1249: x (NCHW f32) -> xt (N,spatial,ic bf16), in-register gather
//   (verified R5-R7). xt elem = (n*160000 + spatial)*16 + ic.
// blocks 1250..1411: w (ic,oc,tap f32) -> wt [tap][ic8][oc][ic_lo] bf16.
__global__ __launch_bounds__(256) void prepass(const float* __restrict__ x,
                                               const float* __restrict__ w,
                                               ushort_t* __restrict__ xt,
                                               ushort_t* __restrict__ wt) {
    const int blk = blockIdx.x;
    if (blk < 1250) {
        const int g = blk * 256 + threadIdx.x;          // 0..319999
        const int n = g / 160000, rem = g % 160000;
        const float* xs = x + (size_t)n * 2560000 + rem;
        unsigned int pk[8];
        #pragma unroll
        for (int e = 0; e < 8; ++e) {
            unsigned int lo = f2bf(xs[(size_t)(2 * e) * 160000]);
            unsigned int hi = f2bf(xs[(size_t)(2 * e + 1) * 160000]);
            pk[e] = lo | (hi << 16);
        }
        uint4v* q = (uint4v*)xt + (size_t)g * 2;
        uint4v q0; q0[0] = pk[0]; q0[1] = pk[1]; q0[2] = pk[2]; q0[3] = pk[3];
        uint4v q1; q1[0] = pk[4]; q1[1] = pk[5]; q1[2] = pk[6]; q1[3] = pk[7];
        q[0] = q0; q[1] = q1;
    } else {
        const int s = (blk - 1250) * 256 + threadIdx.x;
        if (s < 41472) {
            const int ic = s / 2592, rem = s % 2592;
            const int oc = rem / 81, tap = rem % 81;
            wt[tap * 512 + (ic >> 3) * 256 + oc * 8 + (ic & 7)] = f2bf(w[s]);
        }
    }
}

// ---------- main conv ----------
__global__ __launch_bounds__(256, 2) void conv4d_mfma(
    const ushort_t* __restrict__ xt, const ushort_t* __restrict__ wt,
    float* __restrict__ out)
{
    __shared__ ushort_t lx[2][6400];        // double-buffered x slab, 12.8KB each
    __shared__ ushort_t lwt[2][4608];       // double-buffered wt tap-block, 9.2KB each
    __shared__ float edgebuf[4][3][2][16];  // [wv][e1|e2a|e2b][ic8][r]

    // bijective XCD swizzle: 648 blocks = 8 XCDs x 81 contiguous tiles
    const int wgid = blockIdx.x;
    const int tile_ = (wgid & 7) * 81 + (wgid >> 3);
    const int n = tile_ / 324;
    const int rem_ = tile_ - n * 324;
    const int j = rem_ / 18, i = rem_ % 18;

    const int t = threadIdx.x;
    const int lane = t & 63, wv = t >> 6;
    const int col = lane & 31, ic8 = lane >> 5;

    // slab-pos per tile m; reads at spc + c*20 (<= +40); clamp base to 359
    int sp[3]; int cb[3];
    #pragma unroll
    for (int m = 0; m < 3; ++m) {
        sp[m] = (3 * wv + m) * 32 + col;
        const int spc = sp[m] > 359 ? 359 : sp[m];
        cb[m] = spc * 32 + ic8 * 16;       // BYTES into slab
    }
    // A-frag byte offset within a 1024B tap block: contiguous wave sweep
    const int aoffB = ic8 * 512 + col * 16;

    f32x16 acc[3][3];   // [d][m]
    #pragma unroll
    for (int d = 0; d < 3; ++d)
        #pragma unroll
        for (int m = 0; m < 3; ++m)
            #pragma unroll
            for (int r = 0; r < 16; ++r) acc[d][m][r] = 0.0f;

    const ushort_t* xbase = xt + (size_t)n * 2560000;

    // prologue: DMA slab (a=0,b=0) into lx[0], wt taps 0..8 into lwt[0]
    {
        const ushort_t* g = xbase + (size_t)i * 128000 + (size_t)j * 6400;
        ushort_t* l0 = lx[0] + (wv << 9);
        const ushort_t* gt = g + t * 8;
        gload16(gt,        l0);
        gload16(gt + 2048, l0 + 2048);
        gload16(gt + 4096, l0 + 4096);
        if (t < 32) gload16(g + 6144 + t * 8, lx[0] + 6144);

        const ushort_t* gw = wt;
        gload16(gw + t * 8,        lwt[0] + (wv << 9));
        gload16(gw + 2048 + t * 8, lwt[0] + 2048 + (wv << 9));
        if (t < 64) gload16(gw + 4096 + t * 8, lwt[0] + 4096);
    }

    int cur = 0;
    for (int ab = 0; ab < 9; ++ab) {
        __syncthreads();   // drains vmcnt: slab[cur] + lwt[ab&1] complete

        const int nxt = ab + 1;
        if (ab < 8) {      // DMA next slab + next tap-block, hides under MFMA
            const int a = nxt / 3, b = nxt % 3;
            const ushort_t* g = xbase + (size_t)(i + a) * 128000 + (size_t)(j + b) * 6400;
            ushort_t* lb = lx[cur ^ 1];
            ushort_t* l0 = lb + (wv << 9);
            const ushort_t* gt = g + t * 8;
            gload16(gt,        l0);
            gload16(gt + 2048, l0 + 2048);
            gload16(gt + 4096, l0 + 4096);
            if (t < 32) gload16(g + 6144 + t * 8, lb + 6144);

            const ushort_t* gw = wt + (size_t)nxt * 4608;
            ushort_t* lw = lwt[nxt & 1];
            gload16(gw + t * 8,        lw + (wv << 9));
            gload16(gw + 2048 + t * 8, lw + 2048 + (wv << 9));
            if (t < 64) gload16(gw + 4096 + t * 8, lw + 4096);
        }

        const char* lbase = (const char*)lx[cur];
        const char* wbase = (const char*)lwt[ab & 1];
        #pragma unroll
        for (int c = 0; c < 3; ++c) {
            bf16x8 af0 = *(const bf16x8*)(wbase + (c * 3 + 0) * 1024 + aoffB);
            bf16x8 af1 = *(const bf16x8*)(wbase + (c * 3 + 1) * 1024 + aoffB);
            bf16x8 af2 = *(const bf16x8*)(wbase + (c * 3 + 2) * 1024 + aoffB);
            #pragma unroll
            for (int m = 0; m < 3; ++m) {
                bf16x8 bv = *(const bf16x8*)(lbase + cb[m] + c * 640);
                acc[0][m] = __builtin_amdgcn_mfma_f32_32x32x16_bf16(af0, bv, acc[0][m], 0, 0, 0);
                acc[1][m] = __builtin_amdgcn_mfma_f32_32x32x16_bf16(af1, bv, acc[1][m], 0, 0, 0);
                acc[2][m] = __builtin_amdgcn_mfma_f32_32x32x16_bf16(af2, bv, acc[2][m], 0, 0, 0);
            }
        }

        if (ab < 8) cur ^= 1;
    }

    // ---- epilogue: out(k,l) = acc0[s] + acc1[s+1] + acc2[s+2], s=k*20+l ----
    if (col == 0) {
        #pragma unroll
        for (int r = 0; r < 16; ++r) {
            edgebuf[wv][0][ic8][r] = acc[1][0][r];
            edgebuf[wv][1][ic8][r] = acc[2][0][r];
        }
    } else if (col == 1) {
        #pragma unroll
        for (int r = 0; r < 16; ++r)
            edgebuf[wv][2][ic8][r] = acc[2][0][r];
    }
    __syncthreads();
    const int nw = wv < 3 ? wv + 1 : 3;   // wave3's import is never consumed

    bool valm[3]; float* po[3];
    float* outn = out + (size_t)n * 3359232 + (size_t)i * 5832 + (size_t)j * 324
                      + (size_t)ic8 * 419904;
    #pragma unroll
    for (int m = 0; m < 3; ++m) {
        const int s = sp[m];
        const int k = s / 20, ls = s % 20;
        valm[m] = (ls <= 17) && (s <= 357);
        po[m] = outn + k * 18 + ls;
    }
    const int src1 = (lane & 32) | ((col + 1) & 31);
    const int src2 = (lane & 32) | ((col + 2) & 31);

    #pragma unroll
    for (int r = 0; r < 16; ++r) {
        const float e1  = edgebuf[nw][0][ic8][r];
        const float e2a = edgebuf[nw][1][ic8][r];
        const float e2b = edgebuf[nw][2][ic8][r];
        float t1[4], t2[4];
        #pragma unroll
        for (int m = 0; m < 3; ++m) {
            t1[m] = __shfl(acc[1][m][r], src1, 64);
            t2[m] = __shfl(acc[2][m][r], src2, 64);
        }
        t1[3] = e1;
        t2[3] = (col == 30) ? e2a : e2b;
        const int offr = ((r & 3) + 8 * (r >> 2)) * 104976;
        #pragma unroll
        for (int m = 0; m < 3; ++m) {
            const float v1m = (col == 31) ? t1[m + 1] : t1[m];
            const float v2m = (col >= 30) ? t2[m + 1] : t2[m];
            const float res = acc[0][m][r] + v1m + v2m;
            if (valm[m]) po[m][offr] = res;
        }
    }
}

extern "C" void kernel_launch(void* const* d_in, const int* in_sizes, int n_in,
                              void* d_out, int out_size, void* d_ws, size_t ws_size,
                              hipStream_t stream) {
    const float* x = (const float*)d_in[0];
    const float* w = (const float*)d_in[1];
    float* out = (float*)d_out;

    ushort_t* xt = (ushort_t*)d_ws;                              // 10.24 MB
    ushort_t* wt = (ushort_t*)((char*)d_ws + (size_t)10240000);  // 83 KB

    prepass<<<dim3(1412), 256, 0, stream>>>(x, w, xt, wt);
    conv4d_mfma<<<dim3(648), 256, 0, stream>>>(xt, wt, out);
}